// Round 9
// baseline (1720.177 us; speedup 1.0000x reference)
//
#include <hip/hip_runtime.h>

// ================= numpy-f32 bit-replication, v5 (perf) =================
// FROZEN chains (R6-R8 passed, absmax 0.009765625). This round changes only
// memory movement / scheduling: snn 4-rows/wave + swizzled b128 weight reads
// + slow-path split to separate kernel; gemm reg-prefetch pipeline.

// ---------------- LayerNorm, numpy AVX512-pairwise (verbatim) ----------------
template<int W, bool HASRES>
__global__ __launch_bounds__(256) void ln_np(const float* in, float* out,
        const float* g, const float* b, const float* res, int resStride, int rows)
{
    constexpr int E = W / 64;
    __shared__ float lds[4][W];
    int wave = threadIdx.x >> 6, lane = threadIdx.x & 63;
    int row = blockIdx.x * 4 + wave;
    const float* rp = in + (size_t)row * W;
    float v[E];
    #pragma unroll
    for (int e = 0; e < E; ++e) {
        v[e] = rp[e * 64 + lane];
        lds[wave][e * 64 + lane] = v[e];
    }
    __syncthreads();

    auto reduce_np = [&](const float* p) -> float {
        if constexpr (W == 64) {
            int j = lane & 7;
            float r = p[j];
            #pragma unroll
            for (int i = 8; i < 64; i += 8) r = __fadd_rn(r, p[i + j]);
            r = __fadd_rn(r, __shfl_xor(r, 1));
            r = __fadd_rn(r, __shfl_xor(r, 2));
            r = __fadd_rn(r, __shfl_xor(r, 4));
            return r;
        } else {
            constexpr int NB = W / 128;
            int grp = (lane >> 4) % NB;
            int sub = lane & 15;
            const float* q = p + grp * 128 + sub;
            float t = __fadd_rn(
                __fadd_rn(__fadd_rn(q[0],  q[16]), __fadd_rn(q[32], q[48])),
                __fadd_rn(__fadd_rn(q[64], q[80]), __fadd_rn(q[96], q[112])));
            t = __fadd_rn(t, __shfl_xor(t, 8));
            t = __fadd_rn(t, __shfl_xor(t, 4));
            t = __fadd_rn(t, __shfl_xor(t, 2));
            t = __fadd_rn(t, __shfl_xor(t, 1));
            if constexpr (NB >= 2) t = __fadd_rn(t, __shfl_xor(t, 16));
            if constexpr (NB == 4) t = __fadd_rn(t, __shfl_xor(t, 32));
            return t;
        }
    };

    float m = __fdiv_rn(reduce_np(lds[wave]), (float)W);
    __syncthreads();
    #pragma unroll
    for (int e = 0; e < E; ++e) {
        float d = __fsub_rn(v[e], m);
        lds[wave][e * 64 + lane] = __fmul_rn(d, d);
    }
    __syncthreads();
    float var = __fdiv_rn(reduce_np(lds[wave]), (float)W);
    float vpe = __fadd_rn(var, 1e-5f);
    float rs  = __fdiv_rn(1.0f, __fsqrt_rn(vpe));
    float* op = out + (size_t)row * W;
    #pragma unroll
    for (int e = 0; e < E; ++e) {
        int c = e * 64 + lane;
        float o = __fadd_rn(__fmul_rn(__fmul_rn(__fsub_rn(v[e], m), rs), g[c]), b[c]);
        if (HASRES) o = __fadd_rn(o, res[(size_t)row * resStride + c]);
        op[c] = o;
    }
}

// ------ sgemm-order GEMM v3: 128xTN tile, 8xCPT microtile, reg-prefetch ------
// Per-element chain IDENTICAL to R7/R8: k ascending, acc1 (k<SPLIT) /
// acc2 (k>=SPLIT), join fadd, +bias fadd, optional lrelu.
template<int K, int TN, int SPLIT, bool LRELU>
__global__ __launch_bounds__(256) void gemm2(const float* A, const float* Wt,
        const float* bias, float* out, int ldb, int colOff, int nOut)
{
    constexpr int CPT = TN / 16;                  // 8 (TN=128) or 4 (TN=64)
    constexpr bool TWO = (SPLIT < K);
    constexpr int NF4 = (32 * TN / 4) / 256;      // 4 or 2
    __shared__ __align__(16) float As[32 * 132];  // [k][row], stride 132
    __shared__ __align__(16) float Bs[32 * TN];   // [k][col]
    int tid = threadIdx.x;
    int rg = tid >> 4;                            // 0..15 row-group
    int cg = tid & 15;                            // 0..15 col-group
    int rowBase = blockIdx.x * 128;
    int colTile = blockIdx.y * TN;
    int arow = tid >> 1, akoff = (tid & 1) * 16;
    const float* aBase = &A[(size_t)(rowBase + arow) * K + akoff];
    const float* bBase = &Wt[colOff + colTile];

    float4 pa[4], pb[NF4];
    #pragma unroll
    for (int j = 0; j < 4; ++j)
        pa[j] = *reinterpret_cast<const float4*>(aBase + 4 * j);
    #pragma unroll
    for (int j = 0; j < NF4; ++j) {
        int i = tid + j * 256;
        int k = i / (TN / 4), c4 = i % (TN / 4);
        pb[j] = *reinterpret_cast<const float4*>(&bBase[(size_t)k * ldb + c4 * 4]);
    }

    float acc1[8][CPT];
    float acc2[TWO ? 8 : 1][TWO ? CPT : 1];
    #pragma unroll
    for (int r = 0; r < 8; ++r)
        #pragma unroll
        for (int c = 0; c < CPT; ++c) acc1[r][c] = 0.f;
    if constexpr (TWO) {
        #pragma unroll
        for (int r = 0; r < 8; ++r)
            #pragma unroll
            for (int c = 0; c < CPT; ++c) acc2[r][c] = 0.f;
    }

    for (int kc = 0; kc < K; kc += 32) {
        // write staged regs -> LDS
        #pragma unroll
        for (int j = 0; j < 4; ++j) {
            As[(akoff + 4 * j + 0) * 132 + arow] = pa[j].x;
            As[(akoff + 4 * j + 1) * 132 + arow] = pa[j].y;
            As[(akoff + 4 * j + 2) * 132 + arow] = pa[j].z;
            As[(akoff + 4 * j + 3) * 132 + arow] = pa[j].w;
        }
        #pragma unroll
        for (int j = 0; j < NF4; ++j) {
            int i = tid + j * 256;
            int k = i / (TN / 4), c4 = i % (TN / 4);
            *reinterpret_cast<float4*>(&Bs[k * TN + c4 * 4]) = pb[j];
        }
        __syncthreads();
        // issue next-tile loads (latency hides under compute below)
        if (kc + 32 < K) {
            #pragma unroll
            for (int j = 0; j < 4; ++j)
                pa[j] = *reinterpret_cast<const float4*>(aBase + kc + 32 + 4 * j);
            #pragma unroll
            for (int j = 0; j < NF4; ++j) {
                int i = tid + j * 256;
                int k = i / (TN / 4), c4 = i % (TN / 4);
                pb[j] = *reinterpret_cast<const float4*>(
                    &bBase[(size_t)(kc + 32 + k) * ldb + c4 * 4]);
            }
        }
        bool hi = TWO && (kc >= SPLIT);
        #pragma unroll
        for (int k = 0; k < 32; ++k) {
            float a[8];
            const float4 a0 = *reinterpret_cast<const float4*>(&As[k * 132 + rg * 8]);
            const float4 a1 = *reinterpret_cast<const float4*>(&As[k * 132 + rg * 8 + 4]);
            a[0] = a0.x; a[1] = a0.y; a[2] = a0.z; a[3] = a0.w;
            a[4] = a1.x; a[5] = a1.y; a[6] = a1.z; a[7] = a1.w;
            float bv[CPT];
            const float4 b0 = *reinterpret_cast<const float4*>(&Bs[k * TN + cg * CPT]);
            bv[0] = b0.x; bv[1] = b0.y; bv[2] = b0.z; bv[3] = b0.w;
            if constexpr (CPT == 8) {
                const float4 b1 = *reinterpret_cast<const float4*>(&Bs[k * TN + cg * CPT + 4]);
                bv[4] = b1.x; bv[5] = b1.y; bv[6] = b1.z; bv[7] = b1.w;
            }
            if (!hi) {
                #pragma unroll
                for (int r = 0; r < 8; ++r)
                    #pragma unroll
                    for (int c = 0; c < CPT; ++c)
                        acc1[r][c] = __fmaf_rn(a[r], bv[c], acc1[r][c]);
            } else {
                #pragma unroll
                for (int r = 0; r < 8; ++r)
                    #pragma unroll
                    for (int c = 0; c < CPT; ++c)
                        acc2[r][c] = __fmaf_rn(a[r], bv[c], acc2[r][c]);
            }
        }
        __syncthreads();
    }
    #pragma unroll
    for (int r = 0; r < 8; ++r) {
        int row = rowBase + rg * 8 + r;
        float res[CPT];
        #pragma unroll
        for (int c = 0; c < CPT; ++c) {
            float t = acc1[r][c];
            if constexpr (TWO) t = __fadd_rn(t, acc2[r][c]);
            float v = __fadd_rn(t, bias[colTile + cg * CPT + c]);
            if (LRELU) v = (v >= 0.f) ? v : __fmul_rn(0.1f, v);
            res[c] = v;
        }
        float* orow = &out[(size_t)row * nOut + colTile + cg * CPT];
        *reinterpret_cast<float4*>(orow) = make_float4(res[0], res[1], res[2], res[3]);
        if constexpr (CPT == 8)
            *reinterpret_cast<float4*>(orow + 4) = make_float4(res[4], res[5], res[6], res[7]);
    }
}

// ------- slow path helper: verbatim R7/R8 dual-chain run_pair -------
__device__ void run_pair(float x0, float biasA, float biasB,
    int T, int lane, int l32, int l5,
    const float* lWs1, const float* lWs2, const float* lWs3, const float* lWout,
    const float* lbs1, const float* lbs2, const float* lbs3, const float* lbout,
    float& dA, float& dB, bool& eq)
{
    float tA0 = 0.8f + biasA, tA1 = 0.85f + biasA, tA2 = 0.9f + biasA, tA3 = 0.95f + biasA;
    float tB0 = 0.8f + biasB, tB1 = 0.85f + biasB, tB2 = 0.9f + biasB, tB3 = 0.95f + biasB;
    float mA0 = 0.f, mA1 = 0.f, mA2 = 0.f, mA3 = 0.f, accA = 0.f;
    float mB0 = 0.f, mB1 = 0.f, mB2 = 0.f, mB3 = 0.f, accB = 0.f;
    bool same = true;
    unsigned long long pA3 = ~0ull, pB3 = ~0ull;
    float sgA = 0.f, sgB = 0.f;
    for (int t = 0; t < T; ++t) {
        bool r;
        r = mA0 > tA0; mA0 = r ? 0.f : __fadd_rn(__fmul_rn(0.95f, mA0), x0);
        r = mB0 > tB0; mB0 = r ? 0.f : __fadd_rn(__fmul_rn(0.95f, mB0), x0);
        unsigned long long kA = __ballot(mA0 > tA0);
        unsigned long long kB = __ballot(mB0 > tB0);
        same = same && (kA == kB);
        float hA = 0.f, hB = 0.f;
        #pragma unroll
        for (int i = 0; i < 64; ++i) {
            float w = lWs1[i * 64 + lane];
            hA = __fmaf_rn((float)(int)((kA >> i) & 1), w, hA);
            hB = __fmaf_rn((float)(int)((kB >> i) & 1), w, hB);
        }
        hA = __fadd_rn(hA, lbs1[lane]);
        hB = __fadd_rn(hB, lbs1[lane]);
        r = mA1 > tA1; mA1 = r ? 0.f : __fadd_rn(__fmul_rn(0.92f, mA1), hA);
        r = mB1 > tB1; mB1 = r ? 0.f : __fadd_rn(__fmul_rn(0.92f, mB1), hB);
        kA = __ballot(mA1 > tA1);
        kB = __ballot(mB1 > tB1);
        same = same && (kA == kB);
        hA = 0.f; hB = 0.f;
        #pragma unroll
        for (int i = 0; i < 64; ++i) {
            float w = lWs2[i * 32 + l32];
            hA = __fmaf_rn((float)(int)((kA >> i) & 1), w, hA);
            hB = __fmaf_rn((float)(int)((kB >> i) & 1), w, hB);
        }
        hA = __fadd_rn(hA, lbs2[l32]);
        hB = __fadd_rn(hB, lbs2[l32]);
        r = mA2 > tA2; mA2 = r ? 0.f : __fadd_rn(__fmul_rn(0.9f, mA2), hA);
        r = mB2 > tB2; mB2 = r ? 0.f : __fadd_rn(__fmul_rn(0.9f, mB2), hB);
        kA = __ballot(mA2 > tA2) & 0xffffffffull;
        kB = __ballot(mB2 > tB2) & 0xffffffffull;
        same = same && (kA == kB);
        hA = 0.f; hB = 0.f;
        #pragma unroll
        for (int i = 0; i < 32; ++i) {
            float w = lWs3[i * 32 + l32];
            hA = __fmaf_rn((float)(int)((kA >> i) & 1), w, hA);
            hB = __fmaf_rn((float)(int)((kB >> i) & 1), w, hB);
        }
        hA = __fadd_rn(hA, lbs3[l32]);
        hB = __fadd_rn(hB, lbs3[l32]);
        r = mA3 > tA3; mA3 = r ? 0.f : __fadd_rn(__fmul_rn(0.85f, mA3), hA);
        r = mB3 > tB3; mB3 = r ? 0.f : __fadd_rn(__fmul_rn(0.85f, mB3), hB);
        kA = __ballot(mA3 > tA3) & 0xffffffffull;
        kB = __ballot(mB3 > tB3) & 0xffffffffull;
        same = same && (kA == kB);
        if (kA != pA3) {
            float o = 0.f;
            #pragma unroll
            for (int i = 0; i < 32; ++i)
                o = __fmaf_rn((float)(int)((kA >> i) & 1), lWout[i * 5 + l5], o);
            o = __fadd_rn(o, lbout[l5]);
            sgA = (float)(1.0 / (1.0 + exp(-(double)o)));
            pA3 = kA;
        }
        if (kB != pB3) {
            float o = 0.f;
            #pragma unroll
            for (int i = 0; i < 32; ++i)
                o = __fmaf_rn((float)(int)((kB >> i) & 1), lWout[i * 5 + l5], o);
            o = __fadd_rn(o, lbout[l5]);
            sgB = (float)(1.0 / (1.0 + exp(-(double)o)));
            pB3 = kB;
        }
        accA = __fadd_rn(accA, sgA);
        accB = __fadd_rn(accB, sgB);
    }
    dA = __fdiv_rn(accA, (float)T);
    dB = __fdiv_rn(accB, (float)T);
    eq = same;
}

// ------- SNN v3 fast kernel: 4 rows/wave, swizzled b128 weight reads -------
// Chain ops identical to R8's fast path; mask 'bit?1.0f:0.0f' -> fmaf is
// bit-identical to fmaf((float)bit, w, h). Failing rows recorded for snn_slow.
__global__ __launch_bounds__(256) void snn3(const float* x0buf,
    const float* Ws1, const float* bs1,
    const float* Ws2, const float* bs2,
    const float* Ws3, const float* bs3,
    const float* Wout, const float* bout,
    const int* twp, float* out, int rows, int* faillist)
{
    __shared__ __align__(16) float w1T[4096], w2T[2048], w3T[1024], woT[160];
    __shared__ float lbs1[64], lbs2[32], lbs3[32], lbout[8];
    int tid = threadIdx.x;
    for (int e = tid; e < 4096; e += 256) {
        int l = e & 63, i = e >> 6;
        w1T[l * 64 + (i ^ ((l & 7) << 2))] = Ws1[e];
    }
    for (int e = tid; e < 2048; e += 256) {
        int l = e & 31, i = e >> 5;
        w2T[l * 64 + (i ^ ((l & 7) << 2))] = Ws2[e];
    }
    for (int e = tid; e < 1024; e += 256) {
        int l = e & 31, i = e >> 5;
        w3T[l * 32 + (i ^ ((l & 7) << 2))] = Ws3[e];
    }
    for (int e = tid; e < 160; e += 256) {
        int l = e % 5, i = e / 5;
        woT[l * 32 + (i ^ ((l & 7) << 2))] = Wout[e];
    }
    if (tid < 64) lbs1[tid] = bs1[tid];
    if (tid < 32) { lbs2[tid] = bs2[tid]; lbs3[tid] = bs3[tid]; }
    if (tid < 5)  lbout[tid] = bout[tid];
    __syncthreads();
    const int T = *twp;
    int lane = tid & 63;
    int l32  = lane & 31;
    int l5   = (lane < 5) ? lane : 0;
    int swz  = (lane & 7) << 2;
    int swz32 = (l32 & 7) << 2;
    int swz5  = (l5 & 7) << 2;
    const float EPS3 = 4e-6f / 3.0f;
    const float bA = -3.0f * EPS3, bB = 3.0f * EPS3;
    const float tA0 = 0.8f + bA, tA1 = 0.85f + bA, tA2 = 0.9f + bA, tA3 = 0.95f + bA;
    const float tB0 = 0.8f + bB, tB1 = 0.85f + bB, tB2 = 0.9f + bB, tB3 = 0.95f + bB;
    int wid = blockIdx.x * 4 + (tid >> 6);
    int nw = gridDim.x * 4;
    int nquad = rows >> 2;
    for (int q = wid; q < nquad; q += nw) {
        int rowb = q * 4;
        float x[4], m0[4], m1[4], m2[4], m3[4], acc[4], sg[4];
        unsigned long long pk3[4];
        bool ok[4];
        #pragma unroll
        for (int r = 0; r < 4; ++r) {
            x[r] = x0buf[(size_t)(rowb + r) * 64 + lane];
            m0[r] = 0.f; m1[r] = 0.f; m2[r] = 0.f; m3[r] = 0.f;
            acc[r] = 0.f; sg[r] = 0.f; pk3[r] = ~0ull; ok[r] = true;
        }
        for (int t = 0; t < T; ++t) {
            // LIF0
            unsigned long long k0[4];
            #pragma unroll
            for (int r = 0; r < 4; ++r) {
                bool rr = m0[r] > tA0;
                m0[r] = rr ? 0.f : __fadd_rn(__fmul_rn(0.95f, m0[r]), x[r]);
                k0[r] = __ballot(m0[r] > tA0);
                ok[r] = ok[r] && (k0[r] == __ballot(m0[r] > tB0));
            }
            // layer 1: h = sum_{i asc} mask*w1T + bs1
            float h[4] = {0.f, 0.f, 0.f, 0.f};
            unsigned lo[4], hi[4];
            #pragma unroll
            for (int r = 0; r < 4; ++r) { lo[r] = (unsigned)k0[r]; hi[r] = (unsigned)(k0[r] >> 32); }
            #pragma unroll
            for (int i0 = 0; i0 < 64; i0 += 4) {
                const float4 wv = *reinterpret_cast<const float4*>(&w1T[lane * 64 + (i0 ^ swz)]);
                #pragma unroll
                for (int j = 0; j < 4; ++j) {
                    const int i = i0 + j;
                    const float w = (i == i0) ? wv.x : (i == i0 + 1) ? wv.y : (i == i0 + 2) ? wv.z : wv.w;
                    #pragma unroll
                    for (int r = 0; r < 4; ++r) {
                        unsigned bits = (i < 32) ? lo[r] : hi[r];
                        float mf = ((bits >> (i & 31)) & 1u) ? 1.0f : 0.0f;
                        h[r] = __fmaf_rn(mf, w, h[r]);
                    }
                }
            }
            unsigned long long k1[4];
            #pragma unroll
            for (int r = 0; r < 4; ++r) {
                h[r] = __fadd_rn(h[r], lbs1[lane]);
                bool rr = m1[r] > tA1;
                m1[r] = rr ? 0.f : __fadd_rn(__fmul_rn(0.92f, m1[r]), h[r]);
                k1[r] = __ballot(m1[r] > tA1);
                ok[r] = ok[r] && (k1[r] == __ballot(m1[r] > tB1));
            }
            // layer 2
            #pragma unroll
            for (int r = 0; r < 4; ++r) { h[r] = 0.f; lo[r] = (unsigned)k1[r]; hi[r] = (unsigned)(k1[r] >> 32); }
            #pragma unroll
            for (int i0 = 0; i0 < 64; i0 += 4) {
                const float4 wv = *reinterpret_cast<const float4*>(&w2T[l32 * 64 + (i0 ^ swz32)]);
                #pragma unroll
                for (int j = 0; j < 4; ++j) {
                    const int i = i0 + j;
                    const float w = (i == i0) ? wv.x : (i == i0 + 1) ? wv.y : (i == i0 + 2) ? wv.z : wv.w;
                    #pragma unroll
                    for (int r = 0; r < 4; ++r) {
                        unsigned bits = (i < 32) ? lo[r] : hi[r];
                        float mf = ((bits >> (i & 31)) & 1u) ? 1.0f : 0.0f;
                        h[r] = __fmaf_rn(mf, w, h[r]);
                    }
                }
            }
            unsigned k2[4];
            #pragma unroll
            for (int r = 0; r < 4; ++r) {
                h[r] = __fadd_rn(h[r], lbs2[l32]);
                bool rr = m2[r] > tA2;
                m2[r] = rr ? 0.f : __fadd_rn(__fmul_rn(0.9f, m2[r]), h[r]);
                k2[r] = (unsigned)(__ballot(m2[r] > tA2) & 0xffffffffull);
                ok[r] = ok[r] && (k2[r] == (unsigned)(__ballot(m2[r] > tB2) & 0xffffffffull));
            }
            // layer 3
            #pragma unroll
            for (int r = 0; r < 4; ++r) h[r] = 0.f;
            #pragma unroll
            for (int i0 = 0; i0 < 32; i0 += 4) {
                const float4 wv = *reinterpret_cast<const float4*>(&w3T[l32 * 32 + (i0 ^ swz32)]);
                #pragma unroll
                for (int j = 0; j < 4; ++j) {
                    const int i = i0 + j;
                    const float w = (i == i0) ? wv.x : (i == i0 + 1) ? wv.y : (i == i0 + 2) ? wv.z : wv.w;
                    #pragma unroll
                    for (int r = 0; r < 4; ++r) {
                        float mf = ((k2[r] >> i) & 1u) ? 1.0f : 0.0f;
                        h[r] = __fmaf_rn(mf, w, h[r]);
                    }
                }
            }
            unsigned long long k3[4];
            #pragma unroll
            for (int r = 0; r < 4; ++r) {
                h[r] = __fadd_rn(h[r], lbs3[l32]);
                bool rr = m3[r] > tA3;
                m3[r] = rr ? 0.f : __fadd_rn(__fmul_rn(0.85f, m3[r]), h[r]);
                k3[r] = __ballot(m3[r] > tA3) & 0xffffffffull;
                ok[r] = ok[r] && (k3[r] == (__ballot(m3[r] > tB3) & 0xffffffffull));
            }
            // out head + sigmoid, memoized on k3 (uniform branch per row)
            #pragma unroll
            for (int r = 0; r < 4; ++r) {
                if (k3[r] != pk3[r]) {
                    float o = 0.f;
                    unsigned kk = (unsigned)k3[r];
                    #pragma unroll
                    for (int i0 = 0; i0 < 32; i0 += 4) {
                        const float4 wv = *reinterpret_cast<const float4*>(&woT[l5 * 32 + (i0 ^ swz5)]);
                        #pragma unroll
                        for (int j = 0; j < 4; ++j) {
                            const int i = i0 + j;
                            const float w = (i == i0) ? wv.x : (i == i0 + 1) ? wv.y : (i == i0 + 2) ? wv.z : wv.w;
                            float mf = ((kk >> i) & 1u) ? 1.0f : 0.0f;
                            o = __fmaf_rn(mf, w, o);
                        }
                    }
                    o = __fadd_rn(o, lbout[l5]);
                    sg[r] = (float)(1.0 / (1.0 + exp(-(double)o)));
                    pk3[r] = k3[r];
                }
                acc[r] = __fadd_rn(acc[r], sg[r]);
            }
        }
        #pragma unroll
        for (int r = 0; r < 4; ++r) {
            float d = __fdiv_rn(acc[r], (float)T);
            float osum = d + d; osum = osum + d; osum = osum + d;
            if (lane < 5) out[(size_t)(rowb + r) * 5 + lane] = 0.25f * osum;
            if (!ok[r] && lane == 0) {
                int idx = atomicAdd(&faillist[0], 1);
                faillist[1 + idx] = rowb + r;
            }
        }
    }
}

// ------- SNN slow kernel: re-run flagged rows with full 4-pass bracket -------
__global__ __launch_bounds__(256) void snn_slow(const float* x0buf,
    const float* Ws1, const float* bs1,
    const float* Ws2, const float* bs2,
    const float* Ws3, const float* bs3,
    const float* Wout, const float* bout,
    const int* twp, float* out, const int* faillist)
{
    __shared__ float lWs1[4096], lWs2[2048], lWs3[1024], lWout[160];
    __shared__ float lbs1[64], lbs2[32], lbs3[32], lbout[8];
    int tid = threadIdx.x;
    for (int i = tid; i < 4096; i += 256) lWs1[i] = Ws1[i];
    for (int i = tid; i < 2048; i += 256) lWs2[i] = Ws2[i];
    for (int i = tid; i < 1024; i += 256) lWs3[i] = Ws3[i];
    for (int i = tid; i < 160;  i += 256) lWout[i] = Wout[i];
    if (tid < 64) lbs1[tid] = bs1[tid];
    if (tid < 32) { lbs2[tid] = bs2[tid]; lbs3[tid] = bs3[tid]; }
    if (tid < 5)  lbout[tid] = bout[tid];
    __syncthreads();
    const int T = *twp;
    int lane = tid & 63;
    int l32  = lane & 31;
    int l5   = (lane < 5) ? lane : 0;
    const float EPS3 = 4e-6f / 3.0f;
    int nf = faillist[0];
    int wid = blockIdx.x * 4 + (tid >> 6);
    int nw = gridDim.x * 4;
    for (int fi = wid; fi < nf; fi += nw) {
        int row = faillist[1 + fi];
        float xR = x0buf[(size_t)row * 64 + lane];
        float d0, d3, d1, d2; bool e;
        run_pair(xR, -3.0f * EPS3, 3.0f * EPS3, T, lane, l32, l5,
                 lWs1, lWs2, lWs3, lWout, lbs1, lbs2, lbs3, lbout, d0, d3, e);
        run_pair(xR, -1.0f * EPS3, 1.0f * EPS3, T, lane, l32, l5,
                 lWs1, lWs2, lWs3, lWout, lbs1, lbs2, lbs3, lbout, d1, d2, e);
        float osum = d0 + d1; osum = osum + d2; osum = osum + d3;
        if (lane < 5) out[(size_t)row * 5 + lane] = 0.25f * osum;
    }
}

extern "C" void kernel_launch(void* const* d_in, const int* in_sizes, int n_in,
                              void* d_out, int out_size, void* d_ws, size_t ws_size,
                              hipStream_t stream)
{
    (void)n_in; (void)out_size;
    const float* x      = (const float*)d_in[0];
    const float* g_in   = (const float*)d_in[1];
    const float* b_in   = (const float*)d_in[2];
    const float* W_vis  = (const float*)d_in[3];
    const float* b_vis  = (const float*)d_in[4];
    const float* g_vis  = (const float*)d_in[5];
    const float* bg_vis = (const float*)d_in[6];
    const float* W_qkv  = (const float*)d_in[7];
    const float* b_qkv  = (const float*)d_in[8];
    const float* W_o    = (const float*)d_in[9];
    const float* b_o    = (const float*)d_in[10];
    const float* W1     = (const float*)d_in[11];
    const float* b1     = (const float*)d_in[12];
    const float* g1     = (const float*)d_in[13];
    const float* bg1    = (const float*)d_in[14];
    const float* W2     = (const float*)d_in[15];
    const float* b2     = (const float*)d_in[16];
    const float* g2     = (const float*)d_in[17];
    const float* bg2    = (const float*)d_in[18];
    const float* W3     = (const float*)d_in[19];
    const float* b3     = (const float*)d_in[20];
    const float* g3     = (const float*)d_in[21];
    const float* bg3    = (const float*)d_in[22];
    const float* Ws0    = (const float*)d_in[23];
    const float* bs0    = (const float*)d_in[24];
    const float* Ws1    = (const float*)d_in[25];
    const float* bs1    = (const float*)d_in[26];
    const float* Ws2    = (const float*)d_in[27];
    const float* bs2    = (const float*)d_in[28];
    const float* Ws3    = (const float*)d_in[29];
    const float* bs3    = (const float*)d_in[30];
    const float* Wout   = (const float*)d_in[31];
    const float* bout   = (const float*)d_in[32];
    const int*   twp    = (const int*)d_in[33];
    float* out = (float*)d_out;
    float* ws  = (float*)d_ws;

    const int BROWS = in_sizes[0] / 128;

    // Regions (floats/row): A=512 | B=512 | C=256  -> 1280/row,
    // plus fail list: (1 + BROWS) ints at the end of the used region.
    const size_t perRowB = 1280 * 4;
    const size_t RES = ((size_t)BROWS + 4) * 4;
    size_t avail = (ws_size > RES) ? (ws_size - RES) : 0;
    size_t maxRows = avail / perRowB;
    if (maxRows > (size_t)BROWS) maxRows = BROWS;
    int Rch = (int)(maxRows & ~(size_t)127);
    if (Rch <= 0) return;

    for (int r0 = 0; r0 < BROWS; r0 += Rch) {
        int rows = (BROWS - r0 < Rch) ? (BROWS - r0) : Rch;
        float* rA = ws;
        float* rB = rA + (size_t)Rch * 512;
        float* rC = rB + (size_t)Rch * 512;
        int* fail = (int*)(rC + (size_t)Rch * 256);
        dim3 blk(256);
        int rb = rows / 4;
        int gx = rows / 128;

        hipLaunchKernelGGL((ln_np<128,false>), dim3(rb), blk, 0, stream,
                           x + (size_t)r0 * 128, rC, g_in, b_in, nullptr, 0, rows);
        hipLaunchKernelGGL((gemm2<128,128,128,true>), dim3(gx,4), blk, 0, stream,
                           rC, W_vis, b_vis, rA, 512, 0, 512);
        hipLaunchKernelGGL((ln_np<512,false>), dim3(rb), blk, 0, stream,
                           rA, rB, g_vis, bg_vis, nullptr, 0, rows);
        hipLaunchKernelGGL((gemm2<512,128,384,false>), dim3(gx,4), blk, 0, stream,
                           rB, W_qkv, b_qkv + 1024, rA, 1536, 1024, 512);
        hipLaunchKernelGGL((gemm2<512,128,384,false>), dim3(gx,4), blk, 0, stream,
                           rA, W_o, b_o, rB, 512, 0, 512);
        hipLaunchKernelGGL((gemm2<512,128,384,true>), dim3(gx,2), blk, 0, stream,
                           rB, W1, b1, rC, 256, 0, 256);
        hipLaunchKernelGGL((ln_np<256,true>), dim3(rb), blk, 0, stream,
                           rC, rA, g1, bg1, rB, 512, rows);
        hipLaunchKernelGGL((gemm2<256,128,256,true>), dim3(gx,1), blk, 0, stream,
                           rA, W2, b2, rB, 128, 0, 128);
        hipLaunchKernelGGL((ln_np<128,true>), dim3(rb), blk, 0, stream,
                           rB, rC, g2, bg2, rA, 256, rows);
        hipLaunchKernelGGL((gemm2<128,64,128,true>), dim3(gx,1), blk, 0, stream,
                           rC, W3, b3, rA, 64, 0, 64);
        hipLaunchKernelGGL((ln_np<64,true>), dim3(rb), blk, 0, stream,
                           rA, rB, g3, bg3, rC, 128, rows);
        hipLaunchKernelGGL((gemm2<64,64,64,false>), dim3(gx,1), blk, 0, stream,
                           rB, Ws0, bs0, rA, 64, 0, 64);
        hipMemsetAsync(fail, 0, 4, stream);
        hipLaunchKernelGGL(snn3, dim3(2048), blk, 0, stream,
                           rA, Ws1, bs1, Ws2, bs2, Ws3, bs3,
                           Wout, bout, twp, out + (size_t)r0 * 5, rows, fail);
        hipLaunchKernelGGL(snn_slow, dim3(64), blk, 0, stream,
                           rA, Ws1, bs1, Ws2, bs2, Ws3, bs3,
                           Wout, bout, twp, out + (size_t)r0 * 5, fail);
    }
}